// Round 11
// baseline (112.303 us; speedup 1.0000x reference)
//
#include <hip/hip_runtime.h>
#include <math.h>

#define L      2048
#define DDIM   512
#define NBATCH 8
#define BM     128
#define BN     128
#define NTILE  (L / BM)                  // 16
#define NPAIR  (NTILE * (NTILE + 1) / 2) // 136
#define TOTAL_BLOCKS (NBATCH * NPAIR)    // 1088
#define NKS    (DDIM / 16)               // 32 k-steps of 16

#define ALPHA  0.1f
#define BETA   0.3f
#define MARGIN 2.0f

typedef _Float16 f16x8 __attribute__((ext_vector_type(8)));
typedef __attribute__((ext_vector_type(16))) float f32x16;

// ---------------------------------------------------------------------------
// Kernel 1: fp32 -> fp16 + per-row squared norms (exact fp32).
// ---------------------------------------------------------------------------
__global__ __launch_bounds__(256) void conv_kernel(const float* __restrict__ pred,
                                                   _Float16* __restrict__ h,
                                                   float* __restrict__ sq) {
    int w    = threadIdx.x >> 6;
    int lane = threadIdx.x & 63;
    int row  = blockIdx.x * 4 + w;
    const float* p = pred + (size_t)row * DDIM + lane * 8;
    float4 v0 = *(const float4*)(p);
    float4 v1 = *(const float4*)(p + 4);
    float vals[8] = {v0.x, v0.y, v0.z, v0.w, v1.x, v1.y, v1.z, v1.w};
    f16x8 hv;
    float s = 0.0f;
    #pragma unroll
    for (int i = 0; i < 8; ++i) {
        float x = vals[i];
        s = fmaf(x, x, s);
        hv[i] = (_Float16)x;
    }
    *(f16x8*)(h + (size_t)row * DDIM + lane * 8) = hv;
    #pragma unroll
    for (int off = 32; off > 0; off >>= 1) s += __shfl_down(s, off);
    if (lane == 0) sq[row] = s;
}

// ---------------------------------------------------------------------------
// Kernel 2: register-direct fp16 Gram GEMM (NO LDS, NO barriers) + fused loss.
// Data is L2-resident (2.1 MB/batch per XCD); each wave loads its MFMA
// fragments straight from global with immediate k-offsets and interleaves
// load/MFMA 1:1. 128x128 block tile, 4 waves (2x2 of 64x64, 2x2 frags of
// 32x32), mfma_f32_32x32x16_f16, full K unroll (32 steps), depth-1 register
// double-buffer. A/B frag layout: row = l&31, k = (l>>5)*8 + e -> one
// 16B contiguous global_load_dwordx4 per fragment per lane.
// ---------------------------------------------------------------------------
__global__ __launch_bounds__(256) void loss_kernel(
        const _Float16* __restrict__ h,
        const int*   __restrict__ seg,
        const float* __restrict__ sq,
        double*      __restrict__ partials) {
    __shared__ double wred[4];

    int bid = blockIdx.x;
    int n = bid & 7;            // batch -> XCD round-robin (L2 locality)
    int p = bid >> 3;           // 0..135
    int tj = 0;
    while (true) {
        int rl2 = NTILE - tj;
        if (p < rl2) break;
        p -= rl2;
        ++tj;
    }
    int tk = tj + p;
    int j0 = tj * BM, k0 = tk * BN;

    int t    = threadIdx.x;
    int w    = t >> 6;          // 0..3
    int lane = t & 63;
    int wr   = w >> 1, wc = w & 1;     // 64x64 quadrant
    int l31  = lane & 31;
    int hsel = lane >> 5;              // 0/1: k-halfslice of the frag

    const _Float16* baseH = h + (size_t)n * L * DDIM;

    // per-lane fragment base pointers (k advances via immediate offsets)
    const _Float16* pa[2];
    const _Float16* pb[2];
    #pragma unroll
    for (int m = 0; m < 2; ++m)
        pa[m] = baseH + (size_t)(j0 + wr * 64 + m * 32 + l31) * DDIM + hsel * 8;
    #pragma unroll
    for (int nn = 0; nn < 2; ++nn)
        pb[nn] = baseH + (size_t)(k0 + wc * 64 + nn * 32 + l31) * DDIM + hsel * 8;

    f32x16 acc[2][2];
    #pragma unroll
    for (int m = 0; m < 2; ++m)
        #pragma unroll
        for (int nn = 0; nn < 2; ++nn)
            #pragma unroll
            for (int r = 0; r < 16; ++r) acc[m][nn][r] = 0.0f;

    f16x8 a0, a1, b0, b1;
    a0 = *(const f16x8*)(pa[0]);
    a1 = *(const f16x8*)(pa[1]);
    b0 = *(const f16x8*)(pb[0]);
    b1 = *(const f16x8*)(pb[1]);

    #pragma unroll
    for (int ks = 0; ks < NKS; ++ks) {
        f16x8 na0, na1, nb0, nb1;
        if (ks + 1 < NKS) {
            int o = (ks + 1) * 16;          // 16 f16 = 32 B per k-step
            na0 = *(const f16x8*)(pa[0] + o);
            na1 = *(const f16x8*)(pa[1] + o);
            nb0 = *(const f16x8*)(pb[0] + o);
            nb1 = *(const f16x8*)(pb[1] + o);
        }
        acc[0][0] = __builtin_amdgcn_mfma_f32_32x32x16_f16(a0, b0, acc[0][0], 0, 0, 0);
        acc[0][1] = __builtin_amdgcn_mfma_f32_32x32x16_f16(a0, b1, acc[0][1], 0, 0, 0);
        acc[1][0] = __builtin_amdgcn_mfma_f32_32x32x16_f16(a1, b0, acc[1][0], 0, 0, 0);
        acc[1][1] = __builtin_amdgcn_mfma_f32_32x32x16_f16(a1, b1, acc[1][1], 0, 0, 0);
        if (ks + 1 < NKS) {
            a0 = na0; a1 = na1; b0 = nb0; b1 = nb1;
        }
    }

    // ------------------- fused loss epilogue -------------------
    // 32x32 C/D layout: col = lane&31, row = (reg&3) + 8*(reg>>2) + 4*(lane>>5)
    const int*   segb = seg + n * L;
    const float* sqb  = sq + n * L;

    float lsum = 0.0f;
    #pragma unroll
    for (int nn = 0; nn < 2; ++nn) {
        int k = k0 + wc * 64 + nn * 32 + l31;
        float sqk = sqb[k];
        int   sgk = segb[k];
        #pragma unroll
        for (int m = 0; m < 2; ++m)
            #pragma unroll
            for (int r = 0; r < 16; ++r) {
                int j = j0 + wr * 64 + m * 32 + (r & 3) + 8 * (r >> 2) + 4 * hsel;
                float inner = acc[m][nn][r];
                float d2 = fmaxf(sqb[j] + sqk - 2.0f * inner, 0.0f);
                float v;
                if (segb[j] == sgk) {
                    v = ALPHA * d2;
                } else {
                    float dist = sqrtf(d2);
                    float hg = fmaxf(MARGIN - dist, 0.0f);
                    v = BETA * hg * hg;
                }
                lsum += v;
            }
    }

    // per-wave shuffle reduction (no LDS tree -> no bank conflicts)
    double wgt = (tj == tk) ? 1.0 : 2.0;
    double dsum = (double)lsum * wgt;
    #pragma unroll
    for (int off = 32; off > 0; off >>= 1)
        dsum += __shfl_down(dsum, off);
    if (lane == 0) wred[w] = dsum;
    __syncthreads();
    if (t == 0) partials[bid] = (wred[0] + wred[1]) + (wred[2] + wred[3]);
}

// ---------------------------------------------------------------------------
// Kernel 3: deterministic final reduction -> mean.
// ---------------------------------------------------------------------------
__global__ __launch_bounds__(256) void reduce_kernel(const double* __restrict__ partials,
                                                     float* __restrict__ out,
                                                     int nPart, double invCount) {
    __shared__ double red[256];
    int t = threadIdx.x;
    double s = 0.0;
    for (int i = t; i < nPart; i += 256) s += partials[i];
    red[t] = s;
    __syncthreads();
    #pragma unroll
    for (int k = 128; k > 0; k >>= 1) {
        if (t < k) red[t] += red[t + k];
        __syncthreads();
    }
    if (t == 0) out[0] = (float)(red[0] * invCount);
}

extern "C" void kernel_launch(void* const* d_in, const int* in_sizes, int n_in,
                              void* d_out, int out_size, void* d_ws, size_t ws_size,
                              hipStream_t stream) {
    const float* pred = (const float*)d_in[0];
    const int*   seg  = (const int*)d_in[1];
    float* out = (float*)d_out;

    const size_t HALF = (size_t)NBATCH * L * DDIM;
    _Float16* h        = (_Float16*)d_ws;                    // 16.78 MB
    float*    sq       = (float*)(h + HALF);                 // 64 KB
    double*   partials = (double*)(sq + NBATCH * L);         // 8.7 KB

    conv_kernel<<<NBATCH * L / 4, 256, 0, stream>>>(pred, h, sq);
    loss_kernel<<<TOTAL_BLOCKS, 256, 0, stream>>>(h, seg, sq, partials);
    reduce_kernel<<<1, 256, 0, stream>>>(partials, out, TOTAL_BLOCKS,
                                         1.0 / (double)((size_t)NBATCH * L * L));
}

// Round 12
// 64.550 us; speedup vs baseline: 1.7398x; 1.7398x over previous
//
#include <hip/hip_runtime.h>
#include <math.h>

#define L      2048
#define DDIM   512
#define NBATCH 8
#define BM     128
#define BN     128
#define BK     64
#define NKT    (DDIM / BK)               // 8 K-tiles
#define NTILE  (L / BM)                  // 16
#define NPAIR  (NTILE * (NTILE + 1) / 2) // 136
#define TOTAL_BLOCKS (NBATCH * NPAIR)    // 1088

#define ALPHA  0.1f
#define BETA   0.3f
#define MARGIN 2.0f

typedef _Float16 f16x8 __attribute__((ext_vector_type(8)));
typedef __attribute__((ext_vector_type(4))) float f32x4;

// Single buffer (32 KB): A[128 rows x 128B] then B[128 rows x 128B].
// Row = 8 chunks of 8 f16 (16B); physical chunk = logical ^ (row & 7)
// (proven conflict-free in R8: 16-lane b128 phases hit 8 slots x 2 = 2-way).
#define TILE_SH 8192       // f16 per tile (16 KB)

#define GLOAD_LDS16(g, l) __builtin_amdgcn_global_load_lds(              \
    (const __attribute__((address_space(1))) unsigned int*)(g),          \
    (__attribute__((address_space(3))) unsigned int*)(l), 16, 0, 0)

// ---------------------------------------------------------------------------
// Kernel 1: fp32 -> fp16 + per-row squared norms (exact fp32).
// ---------------------------------------------------------------------------
__global__ __launch_bounds__(256) void conv_kernel(const float* __restrict__ pred,
                                                   _Float16* __restrict__ h,
                                                   float* __restrict__ sq) {
    int w    = threadIdx.x >> 6;
    int lane = threadIdx.x & 63;
    int row  = blockIdx.x * 4 + w;
    const float* p = pred + (size_t)row * DDIM + lane * 8;
    float4 v0 = *(const float4*)(p);
    float4 v1 = *(const float4*)(p + 4);
    float vals[8] = {v0.x, v0.y, v0.z, v0.w, v1.x, v1.y, v1.z, v1.w};
    f16x8 hv;
    float s = 0.0f;
    #pragma unroll
    for (int i = 0; i < 8; ++i) {
        float x = vals[i];
        s = fmaf(x, x, s);
        hv[i] = (_Float16)x;
    }
    *(f16x8*)(h + (size_t)row * DDIM + lane * 8) = hv;
    #pragma unroll
    for (int off = 32; off > 0; off >>= 1) s += __shfl_down(s, off);
    if (lane == 0) sq[row] = s;
}

// ---------------------------------------------------------------------------
// Kernel 2: fp16 Gram GEMM + fused loss (m97-faithful structure).
// 128x128 tile, 4 waves (2x2 of 64x64, each 4x4 frags of 16x16),
// mfma_f32_16x16x32_f16 (5-cyc class), BK=64, 8 K-tiles.
// SINGLE 32KB buffer -> 4 blocks/CU (16 waves/CU): cross-block asynchrony
// absorbs the per-phase barrier/drain cost (m114 implicit overlap).
// Per K-tile: sync; STAGE (8 gload_lds); sync (compiler drains vmcnt);
// 2 x {16 ds_read-backed frags, 16 MFMA}. 32 MFMA/wave/phase.
// ---------------------------------------------------------------------------
__global__ __launch_bounds__(256) void loss_kernel(
        const _Float16* __restrict__ h,
        const int*   __restrict__ seg,
        const float* __restrict__ sq,
        double*      __restrict__ partials) {
    __shared__ _Float16 smem[2 * TILE_SH];   // 32 KB
    __shared__ double wred[4];

    int bid = blockIdx.x;
    int n = bid & 7;            // batch -> XCD round-robin (L2 locality)
    int p = bid >> 3;           // 0..135
    int tj = 0;
    while (true) {
        int rl2 = NTILE - tj;
        if (p < rl2) break;
        p -= rl2;
        ++tj;
    }
    int tk = tj + p;
    int j0 = tj * BM, k0 = tk * BN;

    int t    = threadIdx.x;
    int w    = t >> 6;          // 0..3
    int lane = t & 63;
    int wr   = w >> 1, wc = w & 1;     // 64x64 quadrant
    int l15  = lane & 15;
    int lq   = lane >> 4;              // 0..3: k-quarter of the frag

    const _Float16* baseH = h + (size_t)n * L * DDIM;

    // staging: inst i covers rows 8i..8i+7 (1KB). lane -> row rl8=lane>>3,
    // physical chunk pc=lane&7, logical chunk lc = pc ^ rl8 (row&7 == rl8).
    int rl8 = lane >> 3;
    int lc  = (lane & 7) ^ rl8;
    const _Float16* srcA = baseH + (size_t)(j0 + rl8) * DDIM + lc * 8;
    const _Float16* srcB = baseH + (size_t)(k0 + rl8) * DDIM + lc * 8;

    f32x4 acc[4][4];
    #pragma unroll
    for (int m = 0; m < 4; ++m)
        #pragma unroll
        for (int nn = 0; nn < 4; ++nn) acc[m][nn] = (f32x4){0.f, 0.f, 0.f, 0.f};

    #pragma unroll 1
    for (int kt = 0; kt < NKT; ++kt) {
        __syncthreads();               // previous iteration done reading LDS
        // wave w stages A insts {4w..4w+3} and B insts {4w..4w+3}
        #pragma unroll
        for (int q = 0; q < 4; ++q) {
            int inst = w * 4 + q;
            GLOAD_LDS16(srcA + (size_t)(inst * 8) * DDIM + kt * BK,
                        smem + inst * 512);
            GLOAD_LDS16(srcB + (size_t)(inst * 8) * DDIM + kt * BK,
                        smem + TILE_SH + inst * 512);
        }
        __syncthreads();               // compiler drains vmcnt before barrier

        const _Float16* A = smem;
        const _Float16* B = smem + TILE_SH;

        #pragma unroll
        for (int k2 = 0; k2 < 2; ++k2) {         // two K=32 steps
            int kc = k2 * 4 + lq;                // logical chunk 0..7
            f16x8 af[4], bf[4];
            #pragma unroll
            for (int m = 0; m < 4; ++m) {
                int R = wr * 64 + m * 16 + l15;
                af[m] = *(const f16x8*)&A[R * 64 + ((kc ^ (R & 7)) << 3)];
            }
            #pragma unroll
            for (int nn = 0; nn < 4; ++nn) {
                int R = wc * 64 + nn * 16 + l15;
                bf[nn] = *(const f16x8*)&B[R * 64 + ((kc ^ (R & 7)) << 3)];
            }
            #pragma unroll
            for (int m = 0; m < 4; ++m)
                #pragma unroll
                for (int nn = 0; nn < 4; ++nn)
                    acc[m][nn] = __builtin_amdgcn_mfma_f32_16x16x32_f16(
                        af[m], bf[nn], acc[m][nn], 0, 0, 0);
        }
    }

    // ------------------- fused loss epilogue -------------------
    // 16x16 C/D layout: col = lane&15, row = (lane>>4)*4 + reg
    const int*   segb = seg + n * L;
    const float* sqb  = sq + n * L;

    float lsum = 0.0f;
    #pragma unroll
    for (int nn = 0; nn < 4; ++nn) {
        int k = k0 + wc * 64 + nn * 16 + l15;
        float sqk = sqb[k];
        int   sgk = segb[k];
        #pragma unroll
        for (int m = 0; m < 4; ++m)
            #pragma unroll
            for (int reg = 0; reg < 4; ++reg) {
                int j = j0 + wr * 64 + m * 16 + lq * 4 + reg;
                float inner = acc[m][nn][reg];
                float d2 = fmaxf(sqb[j] + sqk - 2.0f * inner, 0.0f);
                float v;
                if (segb[j] == sgk) {
                    v = ALPHA * d2;
                } else {
                    float dist = sqrtf(d2);
                    float hg = fmaxf(MARGIN - dist, 0.0f);
                    v = BETA * hg * hg;
                }
                lsum += v;
            }
    }

    // per-wave shuffle reduction (no LDS tree -> no bank conflicts)
    double wgt = (tj == tk) ? 1.0 : 2.0;
    double dsum = (double)lsum * wgt;
    #pragma unroll
    for (int off = 32; off > 0; off >>= 1)
        dsum += __shfl_down(dsum, off);
    if (lane == 0) wred[w] = dsum;
    __syncthreads();
    if (t == 0) partials[bid] = (wred[0] + wred[1]) + (wred[2] + wred[3]);
}

// ---------------------------------------------------------------------------
// Kernel 3: deterministic final reduction -> mean.
// ---------------------------------------------------------------------------
__global__ __launch_bounds__(256) void reduce_kernel(const double* __restrict__ partials,
                                                     float* __restrict__ out,
                                                     int nPart, double invCount) {
    __shared__ double red[256];
    int t = threadIdx.x;
    double s = 0.0;
    for (int i = t; i < nPart; i += 256) s += partials[i];
    red[t] = s;
    __syncthreads();
    #pragma unroll
    for (int k = 128; k > 0; k >>= 1) {
        if (t < k) red[t] += red[t + k];
        __syncthreads();
    }
    if (t == 0) out[0] = (float)(red[0] * invCount);
}

extern "C" void kernel_launch(void* const* d_in, const int* in_sizes, int n_in,
                              void* d_out, int out_size, void* d_ws, size_t ws_size,
                              hipStream_t stream) {
    const float* pred = (const float*)d_in[0];
    const int*   seg  = (const int*)d_in[1];
    float* out = (float*)d_out;

    const size_t HALF = (size_t)NBATCH * L * DDIM;
    _Float16* h        = (_Float16*)d_ws;                    // 16.78 MB
    float*    sq       = (float*)(h + HALF);                 // 64 KB
    double*   partials = (double*)(sq + NBATCH * L);         // 8.7 KB

    conv_kernel<<<NBATCH * L / 4, 256, 0, stream>>>(pred, h, sq);
    loss_kernel<<<TOTAL_BLOCKS, 256, 0, stream>>>(h, seg, sq, partials);
    reduce_kernel<<<1, 256, 0, stream>>>(partials, out, TOTAL_BLOCKS,
                                         1.0 / (double)((size_t)NBATCH * L * L));
}